// Round 2
// baseline (152.824 us; speedup 1.0000x reference)
//
#include <hip/hip_runtime.h>

// AWQ int4 GEMM: out[64,11008](f32) = x[64,4096](f32) @ dequant(qweight) + bias
// Round 7: fuse the split-K reduction into the gemm (reduce-in-last-block).
//  - convert_x: x f32 -> fp16, and block 0 zeroes the 86 per-nb counters
//    (workspace is poisoned with garbage every iteration, so counters must be
//    re-zeroed; convert_x is stream-ordered before awq_gemm).
//  - awq_gemm (unchanged main loop from round 6: XCD-chunked grid, packed fp16
//    dequant, 4-deep qweight ring): epilogue stores partials with AGENT-scope
//    (sc0/sc1) 8B stores -> bypass the per-XCD L2, land in the shared L3, so
//    they are visible cross-XCD WITHOUT a kernel boundary. Then one acq-rel
//    device-scope fetch_add per block; the 8th arriver for its nb reads all 8
//    partial slices (agent-scope loads, L3 hits), adds bias, writes out.
//  - reduce_out kernel eliminated (one fewer dispatch + launch gap; reduction
//    overlaps the gemm tail, which at 688/256 = 2.69 blocks/CU is 31% idle).

#define KD   4096
#define ND   11008
#define NPW  1376      // ND/8
#define BN   128       // n-columns per block (16 packed dwords = 64B/row/block)
#define KS   8         // split-K factor == number of XCDs
#define KCH  (KD / KS) // 512 = 4 quant groups
#define MD   64
#define NNB  (ND / BN) // 86 n-blocks

using f16   = _Float16;
using f16x2 = __attribute__((ext_vector_type(2))) _Float16;
using f16x4 = __attribute__((ext_vector_type(4))) _Float16;
using f16x8 = __attribute__((ext_vector_type(8))) _Float16;
using f32x4 = __attribute__((ext_vector_type(4))) float;
using u32x4 = __attribute__((ext_vector_type(4))) unsigned int;

// ---- x f32 -> fp16 (262144 elements, 4 per thread); block 0 zeroes counters ----
__global__ __launch_bounds__(256) void convert_x(
    const float* __restrict__ x, f16* __restrict__ xh, int* __restrict__ cnt)
{
    if (blockIdx.x == 0 && threadIdx.x < NNB) cnt[threadIdx.x] = 0;
    const int i = (blockIdx.x * 256 + threadIdx.x) * 4;
    const f32x4 v = *(const f32x4*)(x + i);
    f16x4 r;
    r[0] = (f16)v[0]; r[1] = (f16)v[1];
    r[2] = (f16)v[2]; r[3] = (f16)v[3];
    *(f16x4*)(xh + i) = r;
}

__global__ __launch_bounds__(256) void awq_gemm(
    const f16*   __restrict__ xh,
    const int*   __restrict__ qw,
    const float* __restrict__ sc,
    const int*   __restrict__ qz,
    float*       __restrict__ part,   // [KS][MD][ND]
    int*         __restrict__ cnt,    // [NNB]
    const float* __restrict__ bias,
    float*       __restrict__ out)
{
    const int tid  = threadIdx.x;
    const int wv   = tid >> 6;        // wave 0..3
    const int lane = tid & 63;
    const int l15  = lane & 15;
    const int q4   = lane >> 4;       // quad 0..3

    // XCD-chunked decode: XCD = blockIdx.x % 8 (default round-robin); each XCD
    // owns one contiguous split-K qweight slice, L2-resident, no split lines.
    const int ks = blockIdx.x & 7;
    const int nb = blockIdx.x >> 3;

    const int npw = nb * 16 + l15;    // this lane's packed dword column
    const int sh0 = wv * 4;           // nib c0=2wv at [3:0], c1=2wv+1 at [19:16]
    const int n0  = nb * BN + l15 * 8 + wv * 2;

    const int k_start = ks * KCH;
    const int k_end   = k_start + KCH;

    const int* qwp = qw + npw;
    const f16* xp  = xh + l15 * KD;

    f32x4 acc[2][4] = {};   // [frag][m-tile]

    int   w0[8], w1[8], w2[8], w3[8];   // 4-deep qweight ring
    f16x8 aA[4], aB[4];                 // 2-deep x ping-pong (L2-resident)

    auto LOADQ = [&](int* wb, int k) {
        const int kb = k + q4 * 8;
        #pragma unroll
        for (int j = 0; j < 8; ++j) wb[j] = qwp[(kb + j) * NPW];
    };
    auto LOADA = [&](f16x8* ab, int k) {
        const int kb = k + q4 * 8;
        #pragma unroll
        for (int mt = 0; mt < 4; ++mt)
            ab[mt] = *(const f16x8*)(xp + mt * 16 * KD + kb);
    };

    LOADQ(w0, k_start);       LOADQ(w1, k_start + 32);
    LOADQ(w2, k_start + 64);  LOADQ(w3, k_start + 96);
    LOADA(aA, k_start);       LOADA(aB, k_start + 32);

    // group scalars prefetched one full group ahead
    int    zw_n = qz[(k_start >> 7) * NPW + npw];
    float2 sv_n = *(const float2*)(sc + (k_start >> 7) * ND + n0);

    f16x2 cz, s2;

    auto STEP = [&](const int* wb, const f16x8* ab) {
        unsigned r[8];
        #pragma unroll
        for (int j = 0; j < 8; ++j) {
            const unsigned t = (((unsigned)wb[j]) >> sh0) & 0x000F000Fu;
            const f16x2 q = __builtin_bit_cast(f16x2, t | 0x64006400u); // 1024+nib
            r[j] = __builtin_bit_cast(unsigned, (f16x2)((q - cz) * s2));
        }
        // r[j] = (frag0[j] lo16, frag1[j] hi16); regroup into k-pairs per frag.
        u32x4 p0, p1;
        #pragma unroll
        for (int t2 = 0; t2 < 4; ++t2) {
            p0[t2] = __builtin_amdgcn_perm(r[2*t2+1], r[2*t2], 0x05040100u); // lo
            p1[t2] = __builtin_amdgcn_perm(r[2*t2+1], r[2*t2], 0x07060302u); // hi
        }
        const f16x8 b0 = __builtin_bit_cast(f16x8, p0);
        const f16x8 b1 = __builtin_bit_cast(f16x8, p1);
        #pragma unroll
        for (int mt = 0; mt < 4; ++mt) {
            acc[0][mt] = __builtin_amdgcn_mfma_f32_16x16x32_f16(ab[mt], b0, acc[0][mt], 0, 0, 0);
            acc[1][mt] = __builtin_amdgcn_mfma_f32_16x16x32_f16(ab[mt], b1, acc[1][mt], 0, 0, 0);
        }
    };

    for (int kg = k_start; kg < k_end; kg += 128) {
        {
            const unsigned t = (((unsigned)zw_n) >> sh0) & 0x000F000Fu;
            cz = __builtin_bit_cast(f16x2, t | 0x64006400u);   // 1024+z, exact
            s2[0] = (f16)sv_n.x;
            s2[1] = (f16)sv_n.y;
        }
        if (kg + 128 < k_end) {
            const int gn = (kg + 128) >> 7;
            zw_n = qz[gn * NPW + npw];
            sv_n = *(const float2*)(sc + gn * ND + n0);
        }

        STEP(w0, aA);
        if (kg + 128 < k_end) LOADQ(w0, kg + 128);
        if (kg +  64 < k_end) LOADA(aA, kg + 64);
        STEP(w1, aB);
        if (kg + 160 < k_end) LOADQ(w1, kg + 160);
        if (kg +  96 < k_end) LOADA(aB, kg + 96);
        STEP(w2, aA);
        if (kg + 192 < k_end) LOADQ(w2, kg + 192);
        if (kg + 128 < k_end) LOADA(aA, kg + 128);
        STEP(w3, aB);
        if (kg + 224 < k_end) LOADQ(w3, kg + 224);
        if (kg + 160 < k_end) LOADA(aB, kg + 160);
    }

    // ---- epilogue: agent-scope partial stores (bypass per-XCD L2 -> L3) ----
    // C/D layout: col = l15 (our n index), row = q4*4 + r
    float* pp = part + ks * (MD * ND);
    #pragma unroll
    for (int mt = 0; mt < 4; ++mt) {
        #pragma unroll
        for (int r = 0; r < 4; ++r) {
            const int m = mt * 16 + q4 * 4 + r;
            const float2 v = make_float2(acc[0][mt][r], acc[1][mt][r]);
            __hip_atomic_store((unsigned long long*)(pp + m * ND + n0),
                               __builtin_bit_cast(unsigned long long, v),
                               __ATOMIC_RELAXED, __HIP_MEMORY_SCOPE_AGENT);
        }
    }

    // all 4 waves' stores drained (syncthreads implies vmcnt(0)), then count.
    __syncthreads();
    __shared__ int s_last;
    if (tid == 0) {
        const int old = __hip_atomic_fetch_add(cnt + nb, 1,
                            __ATOMIC_ACQ_REL, __HIP_MEMORY_SCOPE_AGENT);
        s_last = (old == KS - 1);
    }
    __syncthreads();

    if (s_last) {
        // 8th arriver for this nb: reduce all KS slices of columns
        // [nb*128, nb*128+128) x 64 rows, add bias, write out.
        const int cp = tid & 63;        // column pair 0..63
        const int mq = tid >> 6;        // row quarter 0..3
        const int nc = nb * BN + cp * 2;
        const float2 bv = *(const float2*)(bias + nc);
        #pragma unroll 2
        for (int mr = 0; mr < 16; ++mr) {
            const int m = mq * 16 + mr;
            float2 s = bv;   // same order as old reduce_out: bias, then ks 0..7
            #pragma unroll
            for (int k2 = 0; k2 < KS; ++k2) {
                const unsigned long long u = __hip_atomic_load(
                    (const unsigned long long*)(part + k2 * (MD * ND) + m * ND + nc),
                    __ATOMIC_RELAXED, __HIP_MEMORY_SCOPE_AGENT);
                const float2 p = __builtin_bit_cast(float2, u);
                s.x += p.x; s.y += p.y;
            }
            *(float2*)(out + m * ND + nc) = s;
        }
    }
}

extern "C" void kernel_launch(void* const* d_in, const int* in_sizes, int n_in,
                              void* d_out, int out_size, void* d_ws, size_t ws_size,
                              hipStream_t stream) {
    const float* x    = (const float*)d_in[0];
    const int*   qw   = (const int*)d_in[1];
    const float* sc   = (const float*)d_in[2];
    const int*   qz   = (const int*)d_in[3];
    const float* bias = (const float*)d_in[4];
    float*       out  = (float*)d_out;

    f16*   xh   = (f16*)d_ws;                                  // 512 KB
    int*   cnt  = (int*)((char*)d_ws + MD * KD * 2);           // 86 ints (4KB pad)
    float* part = (float*)((char*)d_ws + MD * KD * 2 + 4096);  // KS*MD*ND*4 = 22.5 MB

    convert_x<<<dim3(MD * KD / 1024), 256, 0, stream>>>(x, xh, cnt);
    awq_gemm<<<dim3((ND / BN) * KS), 256, 0, stream>>>(xh, qw, sc, qz, part, cnt, bias, out);
}

// Round 3
// 110.982 us; speedup vs baseline: 1.3770x; 1.3770x over previous
//
#include <hip/hip_runtime.h>

// AWQ int4 GEMM: out[64,11008](f32) = x[64,4096](f32) @ dequant(qweight) + bias
// Round 8: exact revert to round 6 (known-good, 111.5 us).
// Round 7 post-mortem: agent-scope (write-through) partial stores caused 4x
// write amplification (WRITE_SIZE 22.5 -> 90.8 MB) and vmcnt-stalled blocks;
// fused reduce-in-last-block is net -40 us on this part. Write-back L2 partial
// stores + separate reduce_out is the right structure.
//  - XCD-chunked 1-D grid: ks = blockIdx & 7 (== default XCD round-robin), so each
//    XCD owns one contiguous split-K qweight slice (2.8 MB, L2-resident); no 128-B
//    line is split across XCDs.
//  - Packed fp16 dequant: nibbles c0=2w and c1=2w+1 extracted together via one
//    shift+and, biased with 0x6400 (fp16 1024+q); (q - (1024+z)) exact in fp16.
//  - f16 MFMA (16x16x32); x converted f32->fp16.
//  - 4-buffer qweight ring + 2-buffer x ping-pong, group scalars prefetched
//    one full group ahead.
//  - reduce_out: float4 per thread.

#define KD   4096
#define ND   11008
#define NPW  1376      // ND/8
#define BN   128       // n-columns per block (16 packed dwords = 64B/row/block)
#define KS   8         // split-K factor == number of XCDs
#define KCH  (KD / KS) // 512 = 4 quant groups
#define MD   64

using f16   = _Float16;
using f16x2 = __attribute__((ext_vector_type(2))) _Float16;
using f16x4 = __attribute__((ext_vector_type(4))) _Float16;
using f16x8 = __attribute__((ext_vector_type(8))) _Float16;
using f32x4 = __attribute__((ext_vector_type(4))) float;
using u32x4 = __attribute__((ext_vector_type(4))) unsigned int;

// ---- x f32 -> fp16 (262144 elements, 4 per thread) ----
__global__ __launch_bounds__(256) void convert_x(
    const float* __restrict__ x, f16* __restrict__ xh)
{
    const int i = (blockIdx.x * 256 + threadIdx.x) * 4;
    const f32x4 v = *(const f32x4*)(x + i);
    f16x4 r;
    r[0] = (f16)v[0]; r[1] = (f16)v[1];
    r[2] = (f16)v[2]; r[3] = (f16)v[3];
    *(f16x4*)(xh + i) = r;
}

__global__ __launch_bounds__(256) void awq_gemm(
    const f16*   __restrict__ xh,
    const int*   __restrict__ qw,
    const float* __restrict__ sc,
    const int*   __restrict__ qz,
    float*       __restrict__ part)   // [KS][MD][ND]
{
    const int tid  = threadIdx.x;
    const int wv   = tid >> 6;        // wave 0..3
    const int lane = tid & 63;
    const int l15  = lane & 15;
    const int q4   = lane >> 4;       // quad 0..3

    // XCD-chunked decode: XCD = blockIdx.x % 8 (default round-robin); each XCD
    // gets one split-K slice -> each 128B qweight line fetched by exactly one L2.
    const int ks = blockIdx.x & 7;
    const int nb = blockIdx.x >> 3;

    const int npw = nb * 16 + l15;    // this lane's packed dword column
    // logical cols c0=2wv (nibble pos wv) and c1=2wv+1 (nibble pos wv+4):
    // after >> (4*wv), nib0 at [3:0], nib1 at [19:16].
    const int sh0 = wv * 4;
    const int n0  = nb * BN + l15 * 8 + wv * 2;

    const int k_start = ks * KCH;
    const int k_end   = k_start + KCH;

    const int* qwp = qw + npw;
    const f16* xp  = xh + l15 * KD;

    f32x4 acc[2][4] = {};   // [frag][m-tile]

    int   w0[8], w1[8], w2[8], w3[8];   // 4-deep qweight ring
    f16x8 aA[4], aB[4];                 // 2-deep x ping-pong (L2-resident)

    auto LOADQ = [&](int* wb, int k) {
        const int kb = k + q4 * 8;
        #pragma unroll
        for (int j = 0; j < 8; ++j) wb[j] = qwp[(kb + j) * NPW];
    };
    auto LOADA = [&](f16x8* ab, int k) {
        const int kb = k + q4 * 8;
        #pragma unroll
        for (int mt = 0; mt < 4; ++mt)
            ab[mt] = *(const f16x8*)(xp + mt * 16 * KD + kb);
    };

    LOADQ(w0, k_start);       LOADQ(w1, k_start + 32);
    LOADQ(w2, k_start + 64);  LOADQ(w3, k_start + 96);
    LOADA(aA, k_start);       LOADA(aB, k_start + 32);

    // group scalars prefetched one full group ahead
    int    zw_n = qz[(k_start >> 7) * NPW + npw];
    float2 sv_n = *(const float2*)(sc + (k_start >> 7) * ND + n0);

    f16x2 cz, s2;

    auto STEP = [&](const int* wb, const f16x8* ab) {
        unsigned r[8];
        #pragma unroll
        for (int j = 0; j < 8; ++j) {
            const unsigned t = (((unsigned)wb[j]) >> sh0) & 0x000F000Fu;
            const f16x2 q = __builtin_bit_cast(f16x2, t | 0x64006400u); // 1024+nib
            r[j] = __builtin_bit_cast(unsigned, (f16x2)((q - cz) * s2));
        }
        // r[j] = (frag0[j] lo16, frag1[j] hi16); regroup into k-pairs per frag.
        u32x4 p0, p1;
        #pragma unroll
        for (int t2 = 0; t2 < 4; ++t2) {
            p0[t2] = __builtin_amdgcn_perm(r[2*t2+1], r[2*t2], 0x05040100u); // lo
            p1[t2] = __builtin_amdgcn_perm(r[2*t2+1], r[2*t2], 0x07060302u); // hi
        }
        const f16x8 b0 = __builtin_bit_cast(f16x8, p0);
        const f16x8 b1 = __builtin_bit_cast(f16x8, p1);
        #pragma unroll
        for (int mt = 0; mt < 4; ++mt) {
            acc[0][mt] = __builtin_amdgcn_mfma_f32_16x16x32_f16(ab[mt], b0, acc[0][mt], 0, 0, 0);
            acc[1][mt] = __builtin_amdgcn_mfma_f32_16x16x32_f16(ab[mt], b1, acc[1][mt], 0, 0, 0);
        }
    };

    for (int kg = k_start; kg < k_end; kg += 128) {
        {
            const unsigned t = (((unsigned)zw_n) >> sh0) & 0x000F000Fu;
            cz = __builtin_bit_cast(f16x2, t | 0x64006400u);   // 1024+z, exact
            s2[0] = (f16)sv_n.x;
            s2[1] = (f16)sv_n.y;
        }
        if (kg + 128 < k_end) {
            const int gn = (kg + 128) >> 7;
            zw_n = qz[gn * NPW + npw];
            sv_n = *(const float2*)(sc + gn * ND + n0);
        }

        STEP(w0, aA);
        if (kg + 128 < k_end) LOADQ(w0, kg + 128);
        if (kg +  64 < k_end) LOADA(aA, kg + 64);
        STEP(w1, aB);
        if (kg + 160 < k_end) LOADQ(w1, kg + 160);
        if (kg +  96 < k_end) LOADA(aB, kg + 96);
        STEP(w2, aA);
        if (kg + 192 < k_end) LOADQ(w2, kg + 192);
        if (kg + 128 < k_end) LOADA(aA, kg + 128);
        STEP(w3, aB);
        if (kg + 224 < k_end) LOADQ(w3, kg + 224);
        if (kg + 160 < k_end) LOADA(aB, kg + 160);
    }

    // ---- epilogue: plain write-back stores to split-K partial buffer ----
    // C/D layout: col = l15 (our n index), row = q4*4 + r
    float* pp = part + ks * (MD * ND);
    #pragma unroll
    for (int mt = 0; mt < 4; ++mt) {
        #pragma unroll
        for (int r = 0; r < 4; ++r) {
            const int m = mt * 16 + q4 * 4 + r;
            *(float2*)(pp + m * ND + n0) = make_float2(acc[0][mt][r], acc[1][mt][r]);
        }
    }
}

// ---- out[m,n] = bias[n] + sum_ks part[ks][m][n];  grid (ND/256, MD/4) ----
__global__ __launch_bounds__(256) void reduce_out(
    const float* __restrict__ part,
    const float* __restrict__ bias,
    float*       __restrict__ out)
{
    const int lane = threadIdx.x & 63;
    const int sub  = threadIdx.x >> 6;
    const int n = blockIdx.x * 256 + lane * 4;
    const int m = blockIdx.y * 4 + sub;
    f32x4 s = *(const f32x4*)(bias + n);
    #pragma unroll
    for (int ks = 0; ks < KS; ++ks)
        s += *(const f32x4*)(part + ks * (MD * ND) + m * ND + n);
    *(f32x4*)(out + m * ND + n) = s;
}

extern "C" void kernel_launch(void* const* d_in, const int* in_sizes, int n_in,
                              void* d_out, int out_size, void* d_ws, size_t ws_size,
                              hipStream_t stream) {
    const float* x    = (const float*)d_in[0];
    const int*   qw   = (const int*)d_in[1];
    const float* sc   = (const float*)d_in[2];
    const int*   qz   = (const int*)d_in[3];
    const float* bias = (const float*)d_in[4];
    float*       out  = (float*)d_out;

    f16*   xh   = (f16*)d_ws;                           // 512 KB
    float* part = (float*)((char*)d_ws + MD * KD * 2);  // KS*MD*ND*4 = 22.5 MB

    convert_x<<<dim3(MD * KD / 1024), 256, 0, stream>>>(x, xh);
    awq_gemm<<<dim3((ND / BN) * KS), 256, 0, stream>>>(xh, qw, sc, qz, part);
    reduce_out<<<dim3(ND / 256, MD / 4), 256, 0, stream>>>(part, bias, out);
}